// Round 1
// baseline (606.090 us; speedup 1.0000x reference)
//
#include <hip/hip_runtime.h>
#include <cstdint>
#include <cstddef>

// Problem constants (fixed by the harness): B=4, P=500000, C=32, H=512, W=512.
// B, P, C are derived from in_sizes at launch; H/W are compile-time (scalar
// inputs live on-device and can't be read during graph capture).
#define TH 256

// ---------------------------------------------------------------------------
// Projection helper: reproduces _rasterize_one's math in f32.
// E is (3,4) row-major; Xax=E[:,0], Yax=E[:,1], Zax=E[:,2], T=E[:,3].
// ---------------------------------------------------------------------------
__device__ __forceinline__ bool project_point(
    const float* __restrict__ pc, const float* __restrict__ K,
    const float* __restrict__ E, const float* __restrict__ nf,
    int b, int p, int P, int Hh, int Ww,
    int& pix_out, float& zc_out)
{
    const int i = b * P + p;
    const float x = pc[3 * i + 0];
    const float y = pc[3 * i + 1];
    const float z = pc[3 * i + 2];

    const float* Eb = E + b * 12;
    const float Xx = Eb[0], Yx = Eb[1], Zx = Eb[2],  Tx = Eb[3];
    const float Xy = Eb[4], Yy = Eb[5], Zy = Eb[6],  Ty = Eb[7];
    const float Xz = Eb[8], Yz = Eb[9], Zz = Eb[10], Tz = Eb[11];

    const float dx = x - Tx, dy = y - Ty, dz = z - Tz;
    const float zc = dx * Zx + dy * Zy + dz * Zz;
    const float zs = (zc == 0.0f) ? 1.0f : zc;

    const float* Kb = K + b * 9;
    const float u = Kb[0] * (dx * Xx + dy * Xy + dz * Xz) / zs + Kb[2];
    const float v = Kb[4] * (dx * Yx + dy * Yy + dz * Yz) / zs + Kb[5];

    const int ui = (int)floorf(u);
    const int vi = (int)floorf(v);

    const float nf0 = nf[b * 3 + 0];
    const float nf1 = nf[b * 3 + 1];

    const bool valid = (zc > nf0) && (zc < nf1) &&
                       (ui >= 0) && (ui < Ww) && (vi >= 0) && (vi < Hh);
    pix_out = vi * Ww + ui;
    zc_out  = zc;
    return valid;
}

// ---------------------------------------------------------------------------
// Pass 1: point-parallel z-buffer. packed = (f32_bits(zc) << 32) | pid.
// atomicMin on the packed word == reference's (min depth, then min pid) exactly
// (positive f32 bits are monotone in value; pid is unique -> total order).
// ---------------------------------------------------------------------------
__global__ void rasterize_kernel(
    const float* __restrict__ pc, const float* __restrict__ K,
    const float* __restrict__ E, const float* __restrict__ nf,
    unsigned long long* __restrict__ packed,
    int P, int Hh, int Ww)
{
    const int b = blockIdx.y;
    const int p = blockIdx.x * blockDim.x + threadIdx.x;
    if (p >= P) return;

    int pix; float zc;
    if (!project_point(pc, K, E, nf, b, p, P, Hh, Ww, pix, zc)) return;

    const unsigned long long pk =
        ((unsigned long long)__float_as_uint(zc) << 32) | (unsigned int)p;
    atomicMin(&packed[(size_t)b * Hh * Ww + pix], pk);
}

// ---------------------------------------------------------------------------
// Pass 2: pixel-parallel finalize. Write depth; empty pixels get defaults.
// Adjacent threads = adjacent pixels -> coalesced (gapped) writes per channel.
// ---------------------------------------------------------------------------
__global__ void finalize_kernel(
    const unsigned long long* __restrict__ packed,
    const float* __restrict__ dflt,
    float* __restrict__ out_feat, float* __restrict__ out_depth,
    int C, int npix)
{
    const int b = blockIdx.y;
    const int pix = blockIdx.x * blockDim.x + threadIdx.x;
    if (pix >= npix) return;

    const size_t gi = (size_t)b * npix + pix;
    const unsigned long long pk = packed[gi];
    const bool empty = (pk == ~0ull);

    out_depth[gi] = empty ? 0.0f : __uint_as_float((unsigned int)(pk >> 32));

    if (empty) {
        float* of = out_feat + ((size_t)b * C) * npix + pix;
        #pragma unroll
        for (int c = 0; c < 32; ++c) {
            if (c < C) of[(size_t)c * npix] = dflt[c];
        }
    }
}

// ---------------------------------------------------------------------------
// Pass 3: point-parallel winner scatter. Re-project; a point is the winner of
// its pixel iff the packed word's low 32 bits == its pid. Feature reads are
// coalesced in p across lanes (stride-1), writes are scattered 4B.
// ---------------------------------------------------------------------------
__global__ void scatter_kernel(
    const float* __restrict__ pc, const float* __restrict__ K,
    const float* __restrict__ E, const float* __restrict__ nf,
    const unsigned long long* __restrict__ packed,
    const float* __restrict__ feats,   // (C, B*P)
    float* __restrict__ out_feat,      // (B, C, H, W)
    int B, int P, int C, int Hh, int Ww)
{
    const int b = blockIdx.y;
    const int p = blockIdx.x * blockDim.x + threadIdx.x;
    if (p >= P) return;

    int pix; float zc;
    if (!project_point(pc, K, E, nf, b, p, P, Hh, Ww, pix, zc)) return;

    const int npix = Hh * Ww;
    const unsigned long long pk = packed[(size_t)b * npix + pix];
    if ((unsigned int)(pk & 0xFFFFFFFFull) != (unsigned int)p) return;

    const size_t stride = (size_t)B * P;      // channel stride in feats
    const size_t src0   = (size_t)b * P + p;  // this point's column
    float* of = out_feat + ((size_t)b * C) * npix + pix;
    #pragma unroll
    for (int c = 0; c < 32; ++c) {
        if (c < C) of[(size_t)c * npix] = feats[(size_t)c * stride + src0];
    }
}

extern "C" void kernel_launch(void* const* d_in, const int* in_sizes, int n_in,
                              void* d_out, int out_size, void* d_ws, size_t ws_size,
                              hipStream_t stream) {
    const float* point_features = (const float*)d_in[0];  // (C, B*P)
    const float* default_feats  = (const float*)d_in[1];  // (C, 1)
    const float* point_clouds   = (const float*)d_in[2];  // (B*P, 3)
    const float* cam_K          = (const float*)d_in[3];  // (B, 3, 3)
    const float* cam_E          = (const float*)d_in[4];  // (B, 3, 4)
    const float* near_far       = (const float*)d_in[5];  // (B, 3)

    const int B  = in_sizes[3] / 9;
    const int BP = in_sizes[2] / 3;
    const int P  = BP / B;
    const int C  = in_sizes[0] / BP;
    const int Hh = 512, Ww = 512;
    const int npix = Hh * Ww;

    unsigned long long* packed = (unsigned long long*)d_ws;  // B*npix*8 = 8 MB

    float* out_feat  = (float*)d_out;                        // (B, C, H, W)
    float* out_depth = (float*)d_out + (size_t)B * C * npix; // (B, 1, H, W)

    hipMemsetAsync(packed, 0xFF, (size_t)B * npix * sizeof(unsigned long long),
                   stream);

    const dim3 blk(TH);
    const dim3 grid_pts((P + TH - 1) / TH, B);
    const dim3 grid_pix((npix + TH - 1) / TH, B);

    rasterize_kernel<<<grid_pts, blk, 0, stream>>>(
        point_clouds, cam_K, cam_E, near_far, packed, P, Hh, Ww);

    finalize_kernel<<<grid_pix, blk, 0, stream>>>(
        packed, default_feats, out_feat, out_depth, C, npix);

    scatter_kernel<<<grid_pts, blk, 0, stream>>>(
        point_clouds, cam_K, cam_E, near_far, packed, point_features,
        out_feat, B, P, C, Hh, Ww);
}

// Round 2
// 229.230 us; speedup vs baseline: 2.6440x; 2.6440x over previous
//
#include <hip/hip_runtime.h>
#include <cstdint>
#include <cstddef>

// Problem constants (fixed by the harness): B=4, P=500000, C=32, H=512, W=512.
#define TH 256

// ---------------------------------------------------------------------------
// Projection helper: reproduces _rasterize_one's math in f32.
// E is (3,4) row-major; Xax=E[:,0], Yax=E[:,1], Zax=E[:,2], T=E[:,3].
// ---------------------------------------------------------------------------
__device__ __forceinline__ bool project_point(
    const float* __restrict__ pc, const float* __restrict__ K,
    const float* __restrict__ E, const float* __restrict__ nf,
    int b, int p, int P, int Hh, int Ww,
    int& pix_out, float& zc_out)
{
    const int i = b * P + p;
    const float x = pc[3 * i + 0];
    const float y = pc[3 * i + 1];
    const float z = pc[3 * i + 2];

    const float* Eb = E + b * 12;
    const float Xx = Eb[0], Yx = Eb[1], Zx = Eb[2],  Tx = Eb[3];
    const float Xy = Eb[4], Yy = Eb[5], Zy = Eb[6],  Ty = Eb[7];
    const float Xz = Eb[8], Yz = Eb[9], Zz = Eb[10], Tz = Eb[11];

    const float dx = x - Tx, dy = y - Ty, dz = z - Tz;
    const float zc = dx * Zx + dy * Zy + dz * Zz;
    const float zs = (zc == 0.0f) ? 1.0f : zc;

    const float* Kb = K + b * 9;
    const float u = Kb[0] * (dx * Xx + dy * Xy + dz * Xz) / zs + Kb[2];
    const float v = Kb[4] * (dx * Yx + dy * Yy + dz * Yz) / zs + Kb[5];

    const int ui = (int)floorf(u);
    const int vi = (int)floorf(v);

    const float nf0 = nf[b * 3 + 0];
    const float nf1 = nf[b * 3 + 1];

    const bool valid = (zc > nf0) && (zc < nf1) &&
                       (ui >= 0) && (ui < Ww) && (vi >= 0) && (vi < Hh);
    pix_out = vi * Ww + ui;
    zc_out  = zc;
    return valid;
}

// ---------------------------------------------------------------------------
// Pass 1: point-parallel z-buffer. packed = (f32_bits(zc) << 32) | pid.
// atomicMin on the packed word == reference's (min depth, then min pid) exactly
// (positive f32 bits are monotone in value; pid is unique -> total order).
// ---------------------------------------------------------------------------
__global__ void rasterize_kernel(
    const float* __restrict__ pc, const float* __restrict__ K,
    const float* __restrict__ E, const float* __restrict__ nf,
    unsigned long long* __restrict__ packed,
    int P, int Hh, int Ww)
{
    const int b = blockIdx.y;
    const int p = blockIdx.x * blockDim.x + threadIdx.x;
    if (p >= P) return;

    int pix; float zc;
    if (!project_point(pc, K, E, nf, b, p, P, Hh, Ww, pix, zc)) return;

    const unsigned long long pk =
        ((unsigned long long)__float_as_uint(zc) << 32) | (unsigned int)p;
    atomicMin(&packed[(size_t)b * Hh * Ww + pix], pk);
}

// ---------------------------------------------------------------------------
// Pass 2a: point-parallel winner -> pixel-major stage.
// Feature reads are coalesced in p across lanes; each winner writes its 32
// channels as 128 CONTIGUOUS bytes (2 fully-dirtied 64B lines, no overfetch).
// ---------------------------------------------------------------------------
__global__ void stage_kernel(
    const float* __restrict__ pc, const float* __restrict__ K,
    const float* __restrict__ E, const float* __restrict__ nf,
    const unsigned long long* __restrict__ packed,
    const float* __restrict__ feats,   // (C, B*P)
    float* __restrict__ stage,         // (B*npix, C) pixel-major
    int B, int P, int C, int Hh, int Ww)
{
    const int b = blockIdx.y;
    const int p = blockIdx.x * blockDim.x + threadIdx.x;
    if (p >= P) return;

    int pix; float zc;
    if (!project_point(pc, K, E, nf, b, p, P, Hh, Ww, pix, zc)) return;

    const int npix = Hh * Ww;
    const unsigned long long pk = packed[(size_t)b * npix + pix];
    if ((unsigned int)(pk & 0xFFFFFFFFull) != (unsigned int)p) return;

    const size_t stride = (size_t)B * P;      // channel stride in feats
    const size_t src0   = (size_t)b * P + p;  // this point's column

    float f[32];
    #pragma unroll
    for (int c = 0; c < 32; ++c) f[c] = feats[(size_t)c * stride + src0];

    float4* dst = (float4*)(stage + ((size_t)b * npix + pix) * 32);
    #pragma unroll
    for (int cc = 0; cc < 8; ++cc) {
        dst[cc] = make_float4(f[4 * cc], f[4 * cc + 1], f[4 * cc + 2], f[4 * cc + 3]);
    }
}

// ---------------------------------------------------------------------------
// Pass 2b: pixel-parallel output. Reads stage (contiguous 128B per pixel),
// writes out_feat channel-planes fully coalesced; fuses depth + default fill.
// ---------------------------------------------------------------------------
__global__ void output_kernel(
    const unsigned long long* __restrict__ packed,
    const float* __restrict__ stage,   // (B*npix, C)
    const float* __restrict__ dflt,    // (C, 1)
    float* __restrict__ out_feat,      // (B, C, H, W)
    float* __restrict__ out_depth,     // (B, 1, H, W)
    int C, int npix)
{
    const int b = blockIdx.y;
    const int pix = blockIdx.x * blockDim.x + threadIdx.x;
    if (pix >= npix) return;

    const size_t gi = (size_t)b * npix + pix;
    const unsigned long long pk = packed[gi];
    const bool empty = (pk == ~0ull);

    out_depth[gi] = empty ? 0.0f : __uint_as_float((unsigned int)(pk >> 32));

    float f[32];
    if (empty) {
        #pragma unroll
        for (int c = 0; c < 32; ++c) f[c] = dflt[c];
    } else {
        const float4* src = (const float4*)(stage + gi * 32);
        #pragma unroll
        for (int cc = 0; cc < 8; ++cc) {
            const float4 v = src[cc];
            f[4 * cc] = v.x; f[4 * cc + 1] = v.y; f[4 * cc + 2] = v.z; f[4 * cc + 3] = v.w;
        }
    }

    float* of = out_feat + ((size_t)b * C) * npix + pix;
    #pragma unroll
    for (int c = 0; c < 32; ++c) of[(size_t)c * npix] = f[c];
}

// ---------------------------------------------------------------------------
// Fallback pass (ws too small): direct point-parallel scatter (R1 behavior).
// ---------------------------------------------------------------------------
__global__ void scatter_kernel(
    const float* __restrict__ pc, const float* __restrict__ K,
    const float* __restrict__ E, const float* __restrict__ nf,
    const unsigned long long* __restrict__ packed,
    const float* __restrict__ feats,
    float* __restrict__ out_feat,
    int B, int P, int C, int Hh, int Ww)
{
    const int b = blockIdx.y;
    const int p = blockIdx.x * blockDim.x + threadIdx.x;
    if (p >= P) return;

    int pix; float zc;
    if (!project_point(pc, K, E, nf, b, p, P, Hh, Ww, pix, zc)) return;

    const int npix = Hh * Ww;
    const unsigned long long pk = packed[(size_t)b * npix + pix];
    if ((unsigned int)(pk & 0xFFFFFFFFull) != (unsigned int)p) return;

    const size_t stride = (size_t)B * P;
    const size_t src0   = (size_t)b * P + p;
    float* of = out_feat + ((size_t)b * C) * npix + pix;
    #pragma unroll
    for (int c = 0; c < 32; ++c) {
        if (c < C) of[(size_t)c * npix] = feats[(size_t)c * stride + src0];
    }
}

__global__ void finalize_kernel(
    const unsigned long long* __restrict__ packed,
    const float* __restrict__ dflt,
    float* __restrict__ out_feat, float* __restrict__ out_depth,
    int C, int npix)
{
    const int b = blockIdx.y;
    const int pix = blockIdx.x * blockDim.x + threadIdx.x;
    if (pix >= npix) return;

    const size_t gi = (size_t)b * npix + pix;
    const unsigned long long pk = packed[gi];
    const bool empty = (pk == ~0ull);

    out_depth[gi] = empty ? 0.0f : __uint_as_float((unsigned int)(pk >> 32));

    if (empty) {
        float* of = out_feat + ((size_t)b * C) * npix + pix;
        #pragma unroll
        for (int c = 0; c < 32; ++c) {
            if (c < C) of[(size_t)c * npix] = dflt[c];
        }
    }
}

extern "C" void kernel_launch(void* const* d_in, const int* in_sizes, int n_in,
                              void* d_out, int out_size, void* d_ws, size_t ws_size,
                              hipStream_t stream) {
    const float* point_features = (const float*)d_in[0];  // (C, B*P)
    const float* default_feats  = (const float*)d_in[1];  // (C, 1)
    const float* point_clouds   = (const float*)d_in[2];  // (B*P, 3)
    const float* cam_K          = (const float*)d_in[3];  // (B, 3, 3)
    const float* cam_E          = (const float*)d_in[4];  // (B, 3, 4)
    const float* near_far       = (const float*)d_in[5];  // (B, 3)

    const int B  = in_sizes[3] / 9;
    const int BP = in_sizes[2] / 3;
    const int P  = BP / B;
    const int C  = in_sizes[0] / BP;
    const int Hh = 512, Ww = 512;
    const int npix = Hh * Ww;

    unsigned long long* packed = (unsigned long long*)d_ws;           // 8 MB
    float* stage = (float*)((char*)d_ws + (size_t)B * npix * 8);      // 134 MB

    const size_t need = (size_t)B * npix * (8 + (size_t)C * 4);

    float* out_feat  = (float*)d_out;                        // (B, C, H, W)
    float* out_depth = (float*)d_out + (size_t)B * C * npix; // (B, 1, H, W)

    hipMemsetAsync(packed, 0xFF, (size_t)B * npix * sizeof(unsigned long long),
                   stream);

    const dim3 blk(TH);
    const dim3 grid_pts((P + TH - 1) / TH, B);
    const dim3 grid_pix((npix + TH - 1) / TH, B);

    rasterize_kernel<<<grid_pts, blk, 0, stream>>>(
        point_clouds, cam_K, cam_E, near_far, packed, P, Hh, Ww);

    if (ws_size >= need && C == 32) {
        stage_kernel<<<grid_pts, blk, 0, stream>>>(
            point_clouds, cam_K, cam_E, near_far, packed, point_features,
            stage, B, P, C, Hh, Ww);
        output_kernel<<<grid_pix, blk, 0, stream>>>(
            packed, stage, default_feats, out_feat, out_depth, C, npix);
    } else {
        finalize_kernel<<<grid_pix, blk, 0, stream>>>(
            packed, default_feats, out_feat, out_depth, C, npix);
        scatter_kernel<<<grid_pts, blk, 0, stream>>>(
            point_clouds, cam_K, cam_E, near_far, packed, point_features,
            out_feat, B, P, C, Hh, Ww);
    }
}